// Round 4
// baseline (41.606 us; speedup 1.0000x reference)
//
#include <hip/hip_runtime.h>

typedef unsigned short u16;
typedef unsigned int u32;
typedef __attribute__((ext_vector_type(8))) __bf16 bf16x8;
typedef __attribute__((ext_vector_type(4))) float f32x4;

#define S_LEN 169
#define SP 192

// ---------------- workspace layout (bytes)
#define W2T_WS 0          // bf16 [256][192] = 98304
#define WPK_WS 98304      // bf16 [48][512] swizzled = 49152
#define KE_WS  147456     // f32 [256][176][16] = 2883584
#define KV_WS  3031040
#define SG_WS  5914624    // sigmoid(r)

// ---------------- G kernel LDS
#define WT_OFF  0         // [48][512] bf16 swz = 49152
#define XT0_OFF 49152     // [96][64] bf16 swz = 12288
#define XT1_OFF 61440
#define G_LDS   73728

// ---------------- S kernel LDS
#define SKE  0            // [176][16] f32
#define SKV  11264
#define SG2  22528        // sigmoid -> gate (in place)
#define SKVT 33792        // [16][192] bf16 swz
#define SRB  39936        // [256][40] bf16
#define SSS  60416        // seg [16][16] f32
#define SOW  61440        // [64][40] bf16
#define S_LDS 66560

#define LGKM_BAR() asm volatile("s_waitcnt lgkmcnt(0)\n\ts_barrier" ::: "memory")

// ---------------- kernel W: w2t (blocks 0..191) + weight pack (blocks 192..195)
__global__ __launch_bounds__(1024) void w2_kernel(
    const float* __restrict__ time_w,
    const float* __restrict__ time_alpha,
    const float* __restrict__ time_beta,
    const float* __restrict__ key_w,
    const float* __restrict__ value_w,
    const float* __restrict__ recep_w,
    char* __restrict__ ws)
{
    __bf16* w2t = (__bf16*)(ws + W2T_WS);
    const int blk = blockIdx.x;
    if (blk >= 192) {                      // weight pack: 12 rows of [48][512] per block
        int p = blk - 192;
        int u = threadIdx.x;
        if (u < 768) {
            int j  = 12 * p + (u >> 6);
            int co = (u & 63) << 3;
            const float* src;
            if (j < 16)      src = key_w   + j * 512 + co;
            else if (j < 32) src = value_w + (j - 16) * 512 + co;
            else             src = recep_w + (j - 32) * 512 + co;
            float4 f0 = *(const float4*)src;
            float4 f1 = *(const float4*)(src + 4);
            bf16x8 pk;
            pk[0]=(__bf16)f0.x; pk[1]=(__bf16)f0.y; pk[2]=(__bf16)f0.z; pk[3]=(__bf16)f0.w;
            pk[4]=(__bf16)f1.x; pk[5]=(__bf16)f1.y; pk[6]=(__bf16)f1.z; pk[7]=(__bf16)f1.w;
            u32 off = (((u32)j << 10) + ((u32)co << 1)) ^ (((u32)(j & 7)) << 4);
            *(bf16x8*)(ws + WPK_WS + off) = pk;
        }
        return;
    }
    __shared__ float tw[256];
    __shared__ float al[256];
    __shared__ float part[4][256];
    const int s = blk;
    const int t = threadIdx.x & 255;
    const int p = threadIdx.x >> 8;
    if (s >= S_LEN) {                      // zero-pad columns 169..191
        if (p == 0) w2t[t * SP + s] = (__bf16)0.f;
        return;
    }
    if (p == 0) { tw[t] = time_w[s * 256 + t]; al[t] = time_alpha[s * 256 + t]; }
    __syncthreads();
    const int u0 = p << 6;
    const int u1 = (u0 + 64 < t + 1) ? (u0 + 64) : (t + 1);
    float acc = 0.f;
    for (int u = u0; u < u1; ++u)
        acc = fmaf(tw[255 + u - t], al[u], acc);
    part[p][t] = acc;
    __syncthreads();
    if (p == 0)
        w2t[t * SP + s] = (__bf16)(time_beta[s * 256 + t] *
                                   (part[0][t] + part[1][t] + part[2][t] + part[3][t]));
}

// ---------------- kernel G: k/v/r GEMM + pointwise epilogue. 512 blocks = (b, half)
__global__ __launch_bounds__(256) void gemm_kernel(
    const float* __restrict__ x,
    const float* __restrict__ key_b,
    const float* __restrict__ value_b,
    const float* __restrict__ recep_b,
    const char* __restrict__ wsr,
    char* __restrict__ ws)
{
    __shared__ __align__(16) char smem[G_LDS];
    const int tid  = threadIdx.x;
    const int lane = tid & 63;
    const int wid  = tid >> 6;      // 0..3
    const int q    = lane >> 4;
    const int hs   = lane & 15;
    const int b    = blockIdx.x >> 1;
    const int half = blockIdx.x & 1;
    const int t0   = half * 88;
    const int nrows = half ? 81 : 88;
    const float* xb = x + (size_t)b * (S_LEN * 512);

    // stage weights: straight copy of pre-swizzled bf16 (48 KB)
    #pragma unroll
    for (int it = 0; it < 12; ++it) {
        int i = tid + (it << 8);
        uint4 cp = *(const uint4*)(wsr + WPK_WS + i * 16);
        *(uint4*)(smem + WT_OFF + i * 16) = cp;
    }

    const float kb = key_b[hs];
    const float vb = value_b[hs];
    const float rb = recep_b[hs];

    f32x4 acc0[3], acc1[3];
    #pragma unroll
    for (int n = 0; n < 3; ++n) { acc0[n] = (f32x4){0.f,0.f,0.f,0.f}; acc1[n] = (f32x4){0.f,0.f,0.f,0.f}; }
    const bool has_m1 = (wid < 2);   // m-tiles: wid and wid+4 (wid<2); 6 tiles over 4 waves

    float4 pfA[3][2]; int pvA[3];
    float4 pfB[3][2]; int pvB[3];

    auto ldchunk = [&](int chunk, float4 (&pf)[3][2], int (&pv)[3]) {
        const bool shifted = chunk < 4;   // cols<256 read row t-1
        #pragma unroll
        for (int it = 0; it < 3; ++it) {
            int i = tid + (it << 8);      // 768 units exactly
            int r = i >> 3;
            bool valid = shifted ? (r < nrows && (t0 + r) >= 1) : (r < nrows);
            pv[it] = valid ? 1 : 0;
            if (valid) {
                int tsrc = t0 + r - (shifted ? 1 : 0);
                const float* src = xb + (size_t)tsrc * 512 + (chunk << 6) + ((i & 7) << 3);
                pf[it][0] = *(const float4*)src;
                pf[it][1] = *(const float4*)(src + 4);
            }
        }
    };

    auto cvtwrite = [&](u32 base, float4 (&pf)[3][2], int (&pv)[3]) {
        #pragma unroll
        for (int it = 0; it < 3; ++it) {
            int i = tid + (it << 8);
            int r = i >> 3, co = (i & 7) << 3;
            bf16x8 p = {(__bf16)0.f,(__bf16)0.f,(__bf16)0.f,(__bf16)0.f,
                        (__bf16)0.f,(__bf16)0.f,(__bf16)0.f,(__bf16)0.f};
            if (pv[it]) {
                p[0]=(__bf16)pf[it][0].x; p[1]=(__bf16)pf[it][0].y;
                p[2]=(__bf16)pf[it][0].z; p[3]=(__bf16)pf[it][0].w;
                p[4]=(__bf16)pf[it][1].x; p[5]=(__bf16)pf[it][1].y;
                p[6]=(__bf16)pf[it][1].z; p[7]=(__bf16)pf[it][1].w;
            }
            u32 off = (((u32)r << 7) + ((u32)co << 1)) ^ (((u32)(r & 7)) << 4);
            *(bf16x8*)(smem + base + off) = p;
        }
    };

    auto mfma_chunk = [&](int chunk, u32 xbase) {
        #pragma unroll
        for (int ks = 0; ks < 2; ++ks) {
            int kc = ks << 5;
            bf16x8 bfr[3];
            #pragma unroll
            for (int nt = 0; nt < 3; ++nt) {
                int j = nt * 16 + hs;
                u32 col = (u32)((chunk << 6) + kc + (q << 3));
                u32 off = (((u32)j << 10) + (col << 1)) ^ (((u32)(j & 7)) << 4);
                bfr[nt] = *(const bf16x8*)(smem + WT_OFF + off);
            }
            {
                int row = wid * 16 + hs;
                u32 off = (((u32)row << 7) + ((u32)(kc + (q << 3)) << 1)) ^ (((u32)(row & 7)) << 4);
                bf16x8 afr = *(const bf16x8*)(smem + xbase + off);
                acc0[0] = __builtin_amdgcn_mfma_f32_16x16x32_bf16(afr, bfr[0], acc0[0], 0,0,0);
                acc0[1] = __builtin_amdgcn_mfma_f32_16x16x32_bf16(afr, bfr[1], acc0[1], 0,0,0);
                acc0[2] = __builtin_amdgcn_mfma_f32_16x16x32_bf16(afr, bfr[2], acc0[2], 0,0,0);
            }
            if (has_m1) {
                int row = (wid + 4) * 16 + hs;
                u32 off = (((u32)row << 7) + ((u32)(kc + (q << 3)) << 1)) ^ (((u32)(row & 7)) << 4);
                bf16x8 afr = *(const bf16x8*)(smem + xbase + off);
                acc1[0] = __builtin_amdgcn_mfma_f32_16x16x32_bf16(afr, bfr[0], acc1[0], 0,0,0);
                acc1[1] = __builtin_amdgcn_mfma_f32_16x16x32_bf16(afr, bfr[1], acc1[1], 0,0,0);
                acc1[2] = __builtin_amdgcn_mfma_f32_16x16x32_bf16(afr, bfr[2], acc1[2], 0,0,0);
            }
        }
    };

    ldchunk(0, pfA, pvA);
    cvtwrite(XT0_OFF, pfA, pvA);
    ldchunk(1, pfA, pvA);
    ldchunk(2, pfB, pvB);
    LGKM_BAR();

    #pragma unroll
    for (int chunk = 0; chunk < 8; ++chunk) {
        const u32 cur = (chunk & 1) ? XT1_OFF : XT0_OFF;
        const u32 nxt = (chunk & 1) ? XT0_OFF : XT1_OFF;
        mfma_chunk(chunk, cur);
        if (chunk < 7) {
            if (chunk & 1) cvtwrite(nxt, pfB, pvB);
            else           cvtwrite(nxt, pfA, pvA);
        }
        LGKM_BAR();
        if (chunk < 5) {
            if (chunk & 1) ldchunk(chunk + 3, pfB, pvB);
            else           ldchunk(chunk + 3, pfA, pvA);
        }
    }

    // epilogue: ke = exp(clip(k)), kv = ke*v, sg = sigmoid(r)  -> ws (f32)
    float* keg = (float*)(ws + KE_WS);
    float* kvg = (float*)(ws + KV_WS);
    float* sgg = (float*)(ws + SG_WS);
    #pragma unroll
    for (int m = 0; m < 2; ++m) {
        if (m == 1 && !has_m1) break;
        const f32x4* A = (m == 0) ? acc0 : acc1;
        int tl = (wid + m * 4) * 16 + (q << 2);
        #pragma unroll
        for (int rg = 0; rg < 4; ++rg) {
            int t_local = tl + rg;
            if (t_local < nrows) {
                int t = t0 + t_local;
                float kk = fminf(fmaxf(A[0][rg] + kb, -60.f), 30.f);
                float ke = __expf(kk);
                size_t o = ((size_t)b * 176 + t) * 16 + hs;
                keg[o] = ke;
                kvg[o] = ke * (A[1][rg] + vb);
                sgg[o] = 1.f / (1.f + __expf(-(A[2][rg] + rb)));
            }
        }
    }
}

// ---------------- kernel S: scan + wkv + out-proj. 256 blocks (one per b)
__global__ __launch_bounds__(256) void scan_kernel(
    const char* __restrict__ wsr,
    const float* __restrict__ out_w, const float* __restrict__ out_b,
    const float* __restrict__ gamma,
    float* __restrict__ out)
{
    __shared__ __align__(16) char smem[S_LDS];
    const int tid  = threadIdx.x;
    const int lane = tid & 63;
    const int wid  = tid >> 6;      // 0..3
    const int q    = lane >> 4;
    const int hs   = lane & 15;
    const int b    = blockIdx.x;
    const __bf16* w2t = (const __bf16*)(wsr + W2T_WS);
    const float4* keb = (const float4*)(wsr + KE_WS + (size_t)b * 11264);
    const float4* kvb = (const float4*)(wsr + KV_WS + (size_t)b * 11264);
    const float4* sgb = (const float4*)(wsr + SG_WS + (size_t)b * 11264);

    // coop loads: ke, kv, sigmoid(r) -> LDS (676 float4 each = 169*16 f32)
    #pragma unroll
    for (int it = 0; it < 3; ++it) {
        int i = tid + (it << 8);
        if (i < 676) {
            ((float4*)(smem + SKE))[i] = keb[i];
            ((float4*)(smem + SKV))[i] = kvb[i];
            ((float4*)(smem + SG2))[i] = sgb[i];
        }
    }
    // stage owT [64][40] bf16 (cols 16..39 zero), zero RB pad cols, zero kvT tail
    for (int i = tid; i < 2560; i += 256) {
        int o = i / 40, c = i - o * 40;
        ((__bf16*)(smem + SOW))[i] = (c < 16) ? (__bf16)out_w[o * 16 + c] : (__bf16)0.f;
    }
    for (int i = tid; i < 4096; i += 256) {
        int row = i >> 4, c = 16 + (i & 15);
        ((__bf16*)(smem + SRB))[row * 40 + c] = (__bf16)0.f;
    }
    for (int i = tid; i < 368; i += 256) {
        int h2 = i & 15; int t = S_LEN + (i >> 4);
        u32 off = ((u32)(h2 * 384 + t * 2)) ^ (((u32)(h2 & 7)) << 4);
        *(__bf16*)(smem + SKVT + off) = (__bf16)0.f;
    }
    __syncthreads();

    float* KE = (float*)(smem + SKE);
    float* KV = (float*)(smem + SKV);
    float* GG = (float*)(smem + SG2);
    float* SEG = (float*)(smem + SSS);
    const int h  = tid & 15;
    const int sg = tid >> 4;
    const int ts = sg * 11;
    const int te = (ts + 11 < S_LEN) ? ts + 11 : S_LEN;
    {
        float ssum = 0.f;
        for (int t = ts; t < te; ++t) ssum += KE[t * 16 + h];
        SEG[sg * 16 + h] = ssum;
    }
    __syncthreads();
    {
        float run = 0.f;
        for (int s2 = 0; s2 < sg; ++s2) run += SEG[s2 * 16 + h];   // broadcast reads
        for (int t = ts; t < te; ++t) {
            run += KE[t * 16 + h];                                 // inclusive cumsum
            u32 off = ((u32)(h * 384 + t * 2)) ^ (((u32)(h & 7)) << 4);
            *(__bf16*)(smem + SKVT + off) = (__bf16)KV[t * 16 + h];
            GG[t * 16 + h] = GG[t * 16 + h] / run;                 // sigmoid/denom
        }
    }
    __syncthreads();

    // wkv: [256 t] x [192 s] @ [192 s][16 c]; A-frags from global w2t (L2/L3-hot)
    f32x4 wa[4];
    #pragma unroll
    for (int mi = 0; mi < 4; ++mi) wa[mi] = (f32x4){0.f,0.f,0.f,0.f};
    #pragma unroll
    for (int s0 = 0; s0 < SP; s0 += 32) {
        int scol = s0 + (q << 3);
        u32 boff = ((u32)(hs * 384 + scol * 2)) ^ (((u32)(hs & 7)) << 4);
        bf16x8 bfr = *(const bf16x8*)(smem + SKVT + boff);
        #pragma unroll
        for (int mi = 0; mi < 4; ++mi) {
            int row = (wid + (mi << 2)) * 16 + hs;
            bf16x8 afr = *(const bf16x8*)(w2t + row * SP + scol);
            wa[mi] = __builtin_amdgcn_mfma_f32_16x16x32_bf16(afr, bfr, wa[mi], 0,0,0);
        }
    }
    #pragma unroll
    for (int mi = 0; mi < 4; ++mi) {
        int tb = (wid + (mi << 2)) * 16 + (q << 2);
        #pragma unroll
        for (int rg = 0; rg < 4; ++rg) {
            int t = tb + rg;
            float fac = (t < S_LEN) ? GG[t * 16 + hs] : 0.5f;
            ((__bf16*)(smem + SRB))[t * 40 + hs] = (__bf16)(wa[mi][rg] * fac);
        }
    }
    __syncthreads();

    // out-proj: [256 t][32 cpad] @ [32 cpad][64 o], then (+out_b)*gamma[t]
    float obv[4];
    #pragma unroll
    for (int nt = 0; nt < 4; ++nt) obv[nt] = out_b[nt * 16 + hs];
    #pragma unroll
    for (int mi = 0; mi < 4; ++mi) {
        int mt = wid + (mi << 2);
        int arow = mt * 16 + hs;
        bf16x8 afr = *(const bf16x8*)(smem + SRB + (u32)(arow * 80 + (q << 4)));
        float gm[4];
        #pragma unroll
        for (int rg = 0; rg < 4; ++rg) gm[rg] = gamma[mt * 16 + (q << 2) + rg];
        #pragma unroll
        for (int nt = 0; nt < 4; ++nt) {
            int orow = nt * 16 + hs;
            bf16x8 bfr = *(const bf16x8*)(smem + SOW + (u32)(orow * 80 + (q << 4)));
            f32x4 zc = (f32x4){0.f,0.f,0.f,0.f};
            f32x4 d = __builtin_amdgcn_mfma_f32_16x16x32_bf16(afr, bfr, zc, 0,0,0);
            #pragma unroll
            for (int rg = 0; rg < 4; ++rg) {
                int t = mt * 16 + (q << 2) + rg;
                out[(size_t)b * 16384 + (size_t)t * 64 + nt * 16 + hs] = (d[rg] + obv[nt]) * gm[rg];
            }
        }
    }
}

extern "C" void kernel_launch(void* const* d_in, const int* in_sizes, int n_in,
                              void* d_out, int out_size, void* d_ws, size_t ws_size,
                              hipStream_t stream) {
    const float* x          = (const float*)d_in[0];
    const float* time_w     = (const float*)d_in[1];
    const float* time_alpha = (const float*)d_in[2];
    const float* time_beta  = (const float*)d_in[3];
    const float* time_gamma = (const float*)d_in[4];
    const float* key_w      = (const float*)d_in[5];
    const float* key_b      = (const float*)d_in[6];
    const float* value_w    = (const float*)d_in[7];
    const float* value_b    = (const float*)d_in[8];
    const float* recep_w    = (const float*)d_in[9];
    const float* recep_b    = (const float*)d_in[10];
    const float* out_w      = (const float*)d_in[11];
    const float* out_b      = (const float*)d_in[12];
    char* ws = (char*)d_ws;

    w2_kernel<<<196, 1024, 0, stream>>>(time_w, time_alpha, time_beta,
                                        key_w, value_w, recep_w, ws);
    gemm_kernel<<<512, 256, 0, stream>>>(x, key_b, value_b, recep_b, ws, ws);
    scan_kernel<<<256, 256, 0, stream>>>(ws, out_w, out_b, time_gamma, (float*)d_out);
}